// Round 9
// baseline (494.472 us; speedup 1.0000x reference)
//
#include <hip/hip_runtime.h>
#include <hip/hip_bf16.h>
#include <math.h>

#define N_NODES 10000
#define NFEAT   2000
#define NFE     256
#define NH      128
#define NHE     64
#define NOUT    20
#define DCAT    192
#define BN_EPS  1e-5f

#define KP      10016        // padded K for transposed activations
#define KSTEPS  313
#define MT      157          // 64-row m-tiles
#define NSPLIT  16           // adjmm split-K
#define KC      20
#define NSPLX   4            // xw split-K
#define MPAD    10048

typedef __attribute__((ext_vector_type(8))) short  bf16x8;
typedef __attribute__((ext_vector_type(4))) float  f32x4;

__device__ __forceinline__ float sigm(float x) { return 1.0f / (1.0f + expf(-x)); }

__device__ __forceinline__ unsigned short f2bf(float x) {
    union { __hip_bfloat16 h; unsigned short u; } c;
    c.h = __float2bfloat16(x);
    return c.u;
}

__device__ __forceinline__ float bf2f(unsigned short u) {
    union { float f; unsigned int i; } c;
    c.i = ((unsigned int)u) << 16;
    return c.f;
}

__device__ __forceinline__ bf16x8 cvt8(const float* v) {
    bf16x8 r;
    #pragma unroll
    for (int i = 0; i < 8; ++i) r[i] = (short)f2bf(v[i]);
    return r;
}

// ---------------------------------------------------------------------------
// adjmm split-K, ping-pong LDS, loads fully overlapped.
// SRC=0: read f32 adj, compute rowsums, and WRITE bf16 adjb copy (L3-sized).
// SRC=1: read bf16 adjb (half bytes, L3-resident), no rowsum.
// REV=1 reverses block order so pass 2 starts on the L3-resident tail.
// ---------------------------------------------------------------------------
template<int REV, int SRC>
__global__ __launch_bounds__(256) void adjmm_kernel(const float* __restrict__ adj,
                                                    unsigned short* __restrict__ adjb,
                                                    const unsigned short* __restrict__ hT,
                                                    unsigned short* __restrict__ part,
                                                    float* __restrict__ part_s)
{
    __shared__ unsigned short sa[2][64 * 32];
    __shared__ unsigned short sb[2][128 * 32];
    const int tid  = threadIdx.x;
    const int lane = tid & 63, w = tid >> 6;
    const int bx   = REV ? (int)gridDim.x - 1 - (int)blockIdx.x : (int)blockIdx.x;
    const int by   = REV ? (int)gridDim.y - 1 - (int)blockIdx.y : (int)blockIdx.y;
    const int m0   = bx * 64;
    const int ks0  = by * KC;
    const int ks1  = min(ks0 + KC, KSTEPS);
    const int r0   = (w & 1) * 32;
    const int c0   = (w >> 1) * 64;

    const int arow = tid >> 2, agrp = tid & 3;
    const size_t abase  = (size_t)min(m0 + arow, N_NODES - 1) * N_NODES;   // f32 src
    const size_t abaseB = (size_t)min(m0 + arow, N_NODES - 1) * KP;        // bf16 copy
    const int bcol = tid >> 1, bg0 = (tid & 1) * 2;

    const int asoff  = arow * 32 + ((agrp ^ (arow & 3)) << 3);
    const int bsoff0 = bcol * 32 + (((bg0 + 0) ^ (bcol & 3)) << 3);
    const int bsoff1 = bcol * 32 + (((bg0 + 1) ^ (bcol & 3)) << 3);

    float rs = 0.f;
    f32x4 acc[2][4];
    #pragma unroll
    for (int i = 0; i < 2; ++i)
        #pragma unroll
        for (int j = 0; j < 4; ++j) acc[i][j] = (f32x4){0.f, 0.f, 0.f, 0.f};

    float av8[8];
    bf16x8 va16, vb0, vb1;
    int cur_kg = 0;
    auto load_step = [&](int ks) {            // loads only — no VALU use
        const int k0 = ks * 32;
        const int kg = k0 + agrp * 8;
        cur_kg = kg;
        if constexpr (SRC == 0) {
            if (kg + 8 <= N_NODES) {
                float4 u0 = *(const float4*)(adj + abase + kg);
                float4 u1 = *(const float4*)(adj + abase + kg + 4);
                av8[0] = u0.x; av8[1] = u0.y; av8[2] = u0.z; av8[3] = u0.w;
                av8[4] = u1.x; av8[5] = u1.y; av8[6] = u1.z; av8[7] = u1.w;
            } else {
                #pragma unroll
                for (int i = 0; i < 8; ++i) av8[i] = 0.f;
            }
        } else {
            va16 = *(const bf16x8*)(adjb + abaseB + kg);
        }
        vb0 = *(const bf16x8*)(hT + (size_t)bcol * KP + k0 + bg0 * 8);
        vb1 = *(const bf16x8*)(hT + (size_t)bcol * KP + k0 + (bg0 + 1) * 8);
    };
    auto write_step = [&](int p) {            // first use of loads: after MFMA
        if constexpr (SRC == 0) {
            #pragma unroll
            for (int i = 0; i < 8; ++i) rs += av8[i];
            bf16x8 cv = cvt8(av8);
            *(bf16x8*)(sa[p] + asoff) = cv;
            *(bf16x8*)(adjb + abaseB + cur_kg) = cv;   // bf16 copy for pass 2
        } else {
            *(bf16x8*)(sa[p] + asoff) = va16;
        }
        *(bf16x8*)(sb[p] + bsoff0) = vb0;
        *(bf16x8*)(sb[p] + bsoff1) = vb1;
    };

    load_step(ks0);
    write_step(0);

    for (int ks = ks0; ks < ks1; ++ks) {
        const int p = (ks - ks0) & 1;
        const bool more = (ks + 1 < ks1);
        if (more) load_step(ks + 1);
        __syncthreads();
        bf16x8 av[2], bv[4];
        #pragma unroll
        for (int rb = 0; rb < 2; ++rb) {
            int row = r0 + rb * 16 + (lane & 15);
            int g   = lane >> 4;
            av[rb] = *(const bf16x8*)(sa[p] + row * 32 + ((g ^ (row & 3)) << 3));
        }
        #pragma unroll
        for (int cb = 0; cb < 4; ++cb) {
            int col = c0 + cb * 16 + (lane & 15);
            int g   = lane >> 4;
            bv[cb] = *(const bf16x8*)(sb[p] + col * 32 + ((g ^ (col & 3)) << 3));
        }
        #pragma unroll
        for (int rb = 0; rb < 2; ++rb)
            #pragma unroll
            for (int cb = 0; cb < 4; ++cb)
                acc[rb][cb] = __builtin_amdgcn_mfma_f32_16x16x32_bf16(av[rb], bv[cb],
                                                                      acc[rb][cb], 0, 0, 0);
        if (more) write_step(p ^ 1);
    }

    if constexpr (SRC == 0) {
        rs += __shfl_xor(rs, 1);
        rs += __shfl_xor(rs, 2);
        if ((tid & 3) == 0) part_s[(size_t)by * MPAD + m0 + arow] = rs;
    }

    // coalesced part store: acc -> LDS bounce (reuse sb) -> 16B stores
    unsigned short* bounce = (unsigned short*)sb;
    __syncthreads();
    #pragma unroll
    for (int rb = 0; rb < 2; ++rb)
        #pragma unroll
        for (int cb = 0; cb < 4; ++cb) {
            int lrb = r0 + rb * 16 + (lane >> 4) * 4;
            int col = c0 + cb * 16 + (lane & 15);
            #pragma unroll
            for (int reg = 0; reg < 4; ++reg)
                bounce[(lrb + reg) * 128 + col] = f2bf(acc[rb][cb][reg]);
        }
    __syncthreads();
    unsigned short* pout = part + (size_t)by * MPAD * NH + (size_t)m0 * NH;
    #pragma unroll
    for (int t = 0; t < 4; ++t) {
        int flat = tid + t * 256;
        *(bf16x8*)(pout + flat * 8) = *(const bf16x8*)(bounce + flat * 8);
    }
}

// ---------------------------------------------------------------------------
// x @ W_in.T split-K (4 chunks of 16 K-steps), pipelined ping-pong.
// by==0 blocks additionally pack LSTM/GS weights to bf16 (wl, wgb) at the end.
// ---------------------------------------------------------------------------
__global__ __launch_bounds__(256) void xw_mfma_kernel(const float* __restrict__ x,
                                                      const float* __restrict__ Wn,
                                                      float* __restrict__ part,
                                                      const float* __restrict__ Wih0,
                                                      const float* __restrict__ Whh0,
                                                      const float* __restrict__ Wih1,
                                                      const float* __restrict__ Whh1,
                                                      const float* __restrict__ Wgs,
                                                      unsigned short* __restrict__ wl,
                                                      unsigned short* __restrict__ wgb)
{
    __shared__ unsigned short sa[2][64 * 32];
    __shared__ unsigned short sb[2][128 * 32];
    const int tid  = threadIdx.x;
    const int lane = tid & 63, w = tid >> 6;
    const int m0   = blockIdx.x * 64;
    const int TOT  = (NFEAT + 31) / 32;                 // 63
    const int s0   = blockIdx.y * 16;
    const int s1   = min(s0 + 16, TOT);
    const int r0   = (w & 1) * 32;
    const int c0   = (w >> 1) * 64;

    const int arow = tid >> 2, agrp = tid & 3;
    const size_t abase = (size_t)min(m0 + arow, N_NODES - 1) * NFEAT;
    const int asoff = arow * 32 + ((agrp ^ (arow & 3)) << 3);
    int bn_[2], bgrp_[2], bsoff_[2];
    #pragma unroll
    for (int t = 0; t < 2; ++t) {
        int gi = tid + t * 256;
        bn_[t] = gi >> 2; bgrp_[t] = gi & 3;
        bsoff_[t] = bn_[t] * 32 + ((bgrp_[t] ^ (bn_[t] & 3)) << 3);
    }

    f32x4 acc[2][4];
    #pragma unroll
    for (int i = 0; i < 2; ++i)
        #pragma unroll
        for (int j = 0; j < 4; ++j) acc[i][j] = (f32x4){0.f, 0.f, 0.f, 0.f};

    float av8[8], bv8[2][8];
    auto load_step = [&](int ks) {
        const int k0 = ks * 32;
        {
            const int kg = k0 + agrp * 8;
            if (kg + 8 <= NFEAT) {
                float4 u0 = *(const float4*)(x + abase + kg);
                float4 u1 = *(const float4*)(x + abase + kg + 4);
                av8[0]=u0.x; av8[1]=u0.y; av8[2]=u0.z; av8[3]=u0.w;
                av8[4]=u1.x; av8[5]=u1.y; av8[6]=u1.z; av8[7]=u1.w;
            } else {
                #pragma unroll
                for (int i = 0; i < 8; ++i) av8[i] = 0.f;
            }
        }
        #pragma unroll
        for (int t = 0; t < 2; ++t) {
            int kg = k0 + bgrp_[t] * 8;
            if (kg + 8 <= NFEAT) {
                float4 u0 = *(const float4*)(Wn + (size_t)bn_[t] * NFEAT + kg);
                float4 u1 = *(const float4*)(Wn + (size_t)bn_[t] * NFEAT + kg + 4);
                bv8[t][0]=u0.x; bv8[t][1]=u0.y; bv8[t][2]=u0.z; bv8[t][3]=u0.w;
                bv8[t][4]=u1.x; bv8[t][5]=u1.y; bv8[t][6]=u1.z; bv8[t][7]=u1.w;
            } else {
                #pragma unroll
                for (int i = 0; i < 8; ++i) bv8[t][i] = 0.f;
            }
        }
    };
    auto write_step = [&](int p) {
        *(bf16x8*)(sa[p] + asoff) = cvt8(av8);
        #pragma unroll
        for (int t = 0; t < 2; ++t)
            *(bf16x8*)(sb[p] + bsoff_[t]) = cvt8(bv8[t]);
    };

    load_step(s0);
    write_step(0);

    for (int ks = s0; ks < s1; ++ks) {
        const int p = (ks - s0) & 1;
        const bool more = (ks + 1 < s1);
        if (more) load_step(ks + 1);
        __syncthreads();
        bf16x8 av[2], bv[4];
        #pragma unroll
        for (int rb = 0; rb < 2; ++rb) {
            int row = r0 + rb * 16 + (lane & 15);
            int g   = lane >> 4;
            av[rb] = *(const bf16x8*)(sa[p] + row * 32 + ((g ^ (row & 3)) << 3));
        }
        #pragma unroll
        for (int cb = 0; cb < 4; ++cb) {
            int col = c0 + cb * 16 + (lane & 15);
            int g   = lane >> 4;
            bv[cb] = *(const bf16x8*)(sb[p] + col * 32 + ((g ^ (col & 3)) << 3));
        }
        #pragma unroll
        for (int rb = 0; rb < 2; ++rb)
            #pragma unroll
            for (int cb = 0; cb < 4; ++cb)
                acc[rb][cb] = __builtin_amdgcn_mfma_f32_16x16x32_bf16(av[rb], bv[cb],
                                                                      acc[rb][cb], 0, 0, 0);
        if (more) write_step(p ^ 1);
    }
    float* pout = part + (size_t)blockIdx.y * MPAD * NH;
    #pragma unroll
    for (int rb = 0; rb < 2; ++rb)
        #pragma unroll
        for (int cb = 0; cb < 4; ++cb) {
            int rowb = m0 + r0 + rb * 16 + (lane >> 4) * 4;
            int col  = c0 + cb * 16 + (lane & 15);
            #pragma unroll
            for (int reg = 0; reg < 4; ++reg)
                pout[(size_t)(rowb + reg) * NH + col] = acc[rb][cb][reg];
        }

    // fold-in: pack weights to bf16 (consumers run after adjmm0/gs0)
    if (blockIdx.y == 0) {
        const int total = 262144 + 65536;
        for (int i = blockIdx.x * 256 + tid; i < total; i += MT * 256) {
            if (i < 262144) {
                int l = i >> 17, rem = i & 131071;
                int n = rem >> 8, k = rem & 255;
                const float* src;
                if (l == 0) src = (k < 128) ? (Wih0 + n * 128 + k) : (Whh0 + n * 128 + (k - 128));
                else        src = (k < 128) ? (Wih1 + n * 128 + k) : (Whh1 + n * 128 + (k - 128));
                wl[i] = f2bf(*src);
            } else {
                int j = i - 262144;
                wgb[j] = f2bf(Wgs[j]);
            }
        }
    }
}

// ---------------------------------------------------------------------------
// h_in = elu(bn_in(sum part + b_in)); also writes h_inT bf16 [128][KP] + pad
// ---------------------------------------------------------------------------
__global__ __launch_bounds__(256) void xw_reduce_kernel(const float* __restrict__ part,
                                                        const float* __restrict__ bias,
                                                        const float* __restrict__ g,
                                                        const float* __restrict__ bb,
                                                        const float* __restrict__ rm,
                                                        const float* __restrict__ rv,
                                                        float* __restrict__ h,
                                                        unsigned short* __restrict__ hT)
{
    __shared__ unsigned short tb[128][8];
    const int tid = threadIdx.x;
    int idx = blockIdx.x * 256 + tid;
    const int c4 = (tid & 31) * 4;
    const int lr = tid >> 5;                       // 0..7
    const int m0g = blockIdx.x * 8;
    const size_t ch = (size_t)MPAD * NH / 4;
    const float4* p = (const float4*)part;
    float a[4] = {0.f, 0.f, 0.f, 0.f};
    #pragma unroll
    for (int c = 0; c < NSPLX; ++c) {
        float4 v = p[c * ch + idx];
        a[0] += v.x; a[1] += v.y; a[2] += v.z; a[3] += v.w;
    }
    float o[4];
    #pragma unroll
    for (int j = 0; j < 4; ++j) {
        int c = c4 + j;
        float sc = g[c] / sqrtf(rv[c] + BN_EPS);
        float t = (a[j] + bias[c] - rm[c]) * sc + bb[c];
        o[j] = t > 0.f ? t : expm1f(t);
        tb[c][lr] = f2bf(o[j]);
    }
    float4 ov; ov.x = o[0]; ov.y = o[1]; ov.z = o[2]; ov.w = o[3];
    *(float4*)(h + (size_t)idx * 4) = ov;
    __syncthreads();
    if (tid < 128) {
        ushort4 v0, v1;
        v0.x = tb[tid][0]; v0.y = tb[tid][1]; v0.z = tb[tid][2]; v0.w = tb[tid][3];
        v1.x = tb[tid][4]; v1.y = tb[tid][5]; v1.z = tb[tid][6]; v1.w = tb[tid][7];
        *(ushort4*)(hT + (size_t)tid * KP + m0g)     = v0;
        *(ushort4*)(hT + (size_t)tid * KP + m0g + 4) = v1;
        if (blockIdx.x == 0) {                     // zero the K-pad [10000,10016)
            ushort4 zz; zz.x = zz.y = zz.z = zz.w = 0;
            #pragma unroll
            for (int q = 0; q < 4; ++q)
                *(ushort4*)(hT + (size_t)tid * KP + 10000 + q * 4) = zz;
        }
    }
}

// ---------------------------------------------------------------------------
// GraphSAGE fused (+nreduce): A = [h | (sum_c bf16 part)/rowsum];
// jk = rownorm(relu(A@Wg^T + bg)); opt. jkT bf16. BM=64, K=256, grid MT.
// ---------------------------------------------------------------------------
template<bool WRITE_T>
__global__ __launch_bounds__(256) void gs_fused_kernel(const float* __restrict__ h,
                                                       const unsigned short* __restrict__ part,
                                                       const float* __restrict__ part_s,
                                                       const unsigned short* __restrict__ Wg,
                                                       const float* __restrict__ bg,
                                                       float* __restrict__ jk,
                                                       unsigned short* __restrict__ jkT)
{
    __shared__ unsigned short sa[64 * 32];
    __shared__ unsigned short sb[128 * 32];
    __shared__ float ssq_l[64][2];
    __shared__ unsigned short tb[WRITE_T ? 128 * 64 : 1];
    const int tid  = threadIdx.x;
    const int lane = tid & 63, w = tid >> 6;
    const int m0   = blockIdx.x * 64;
    const int r0   = (w & 1) * 32;
    const int c0   = (w >> 1) * 64;
    const int arow = tid >> 2, agrp = tid & 3;
    const int mg   = min(m0 + arow, N_NODES - 1);

    float inv;
    {
        float s = 0.f;
        #pragma unroll
        for (int c = 0; c < NSPLIT; ++c) s += part_s[(size_t)c * MPAD + mg];
        inv = 1.0f / s;
    }

    f32x4 acc[2][4];
    #pragma unroll
    for (int i = 0; i < 2; ++i)
        #pragma unroll
        for (int j = 0; j < 4; ++j) acc[i][j] = (f32x4){0.f, 0.f, 0.f, 0.f};

    for (int k0 = 0; k0 < 256; k0 += 32) {
        const int kg = k0 + agrp * 8;
        float a8[8];
        if (kg < 128) {
            const float* asrc = h + (size_t)mg * NH + kg;
            float4 u0 = *(const float4*)asrc;
            float4 u1 = *(const float4*)(asrc + 4);
            a8[0]=u0.x; a8[1]=u0.y; a8[2]=u0.z; a8[3]=u0.w;
            a8[4]=u1.x; a8[5]=u1.y; a8[6]=u1.z; a8[7]=u1.w;
        } else {
            const int cc = kg - 128;
            float s[8] = {0.f,0.f,0.f,0.f,0.f,0.f,0.f,0.f};
            #pragma unroll
            for (int c = 0; c < NSPLIT; ++c) {
                bf16x8 v = *(const bf16x8*)(part + (size_t)c * MPAD * NH + (size_t)mg * NH + cc);
                #pragma unroll
                for (int i = 0; i < 8; ++i) s[i] += bf2f((unsigned short)v[i]);
            }
            #pragma unroll
            for (int i = 0; i < 8; ++i) a8[i] = s[i] * inv;
        }
        bf16x8 b8[2];
        #pragma unroll
        for (int t = 0; t < 2; ++t) {
            int gi = tid + t * 256;
            int n = gi >> 2, grp = gi & 3;
            b8[t] = *(const bf16x8*)(Wg + (size_t)n * 256 + k0 + grp * 8);
        }
        __syncthreads();
        *(bf16x8*)(sa + arow * 32 + ((agrp ^ (arow & 3)) << 3)) = cvt8(a8);
        #pragma unroll
        for (int t = 0; t < 2; ++t) {
            int gi = tid + t * 256;
            int n = gi >> 2, grp = gi & 3;
            *(bf16x8*)(sb + n * 32 + ((grp ^ (n & 3)) << 3)) = b8[t];
        }
        __syncthreads();
        bf16x8 av[2], bv[4];
        #pragma unroll
        for (int rb = 0; rb < 2; ++rb) {
            int row = r0 + rb * 16 + (lane & 15);
            int g   = lane >> 4;
            av[rb] = *(const bf16x8*)(sa + row * 32 + ((g ^ (row & 3)) << 3));
        }
        #pragma unroll
        for (int cb = 0; cb < 4; ++cb) {
            int col = c0 + cb * 16 + (lane & 15);
            int g   = lane >> 4;
            bv[cb] = *(const bf16x8*)(sb + col * 32 + ((g ^ (col & 3)) << 3));
        }
        #pragma unroll
        for (int rb = 0; rb < 2; ++rb)
            #pragma unroll
            for (int cb = 0; cb < 4; ++cb)
                acc[rb][cb] = __builtin_amdgcn_mfma_f32_16x16x32_bf16(av[rb], bv[cb],
                                                                      acc[rb][cb], 0, 0, 0);
    }

    float vv[2][4][4];
    float ps[2][4] = {};
    #pragma unroll
    for (int rb = 0; rb < 2; ++rb)
        #pragma unroll
        for (int cb = 0; cb < 4; ++cb) {
            int colg = c0 + cb * 16 + (lane & 15);
            float b = bg[colg];
            #pragma unroll
            for (int reg = 0; reg < 4; ++reg) {
                float t = fmaxf(acc[rb][cb][reg] + b, 0.f);
                vv[rb][cb][reg] = t;
                ps[rb][reg] += t * t;
            }
        }
    #pragma unroll
    for (int msk = 1; msk < 16; msk <<= 1)
        #pragma unroll
        for (int rb = 0; rb < 2; ++rb)
            #pragma unroll
            for (int reg = 0; reg < 4; ++reg)
                ps[rb][reg] += __shfl_xor(ps[rb][reg], msk);
    if ((lane & 15) == 0) {
        #pragma unroll
        for (int rb = 0; rb < 2; ++rb)
            #pragma unroll
            for (int reg = 0; reg < 4; ++reg)
                ssq_l[r0 + rb * 16 + (lane >> 4) * 4 + reg][w >> 1] = ps[rb][reg];
    }
    __syncthreads();
    #pragma unroll
    for (int rb = 0; rb < 2; ++rb)
        #pragma unroll
        for (int reg = 0; reg < 4; ++reg) {
            int lr = r0 + rb * 16 + (lane >> 4) * 4 + reg;
            float s = ssq_l[lr][0] + ssq_l[lr][1];
            float sc = 1.0f / fmaxf(sqrtf(s), 1e-12f);
            int m = m0 + lr;
            #pragma unroll
            for (int cb = 0; cb < 4; ++cb) {
                int colg = c0 + cb * 16 + (lane & 15);
                float o = vv[rb][cb][reg] * sc;
                if (m < N_NODES) jk[(size_t)m * NH + colg] = o;
                if constexpr (WRITE_T) tb[colg * 64 + lr] = f2bf(o);
            }
        }
    if constexpr (WRITE_T) {
        __syncthreads();
        #pragma unroll
        for (int p = 0; p < 4; ++p) {
            int flat = (tid + p * 256) * 8;
            int c = flat >> 6, mo = flat & 63;
            int kglob = m0 + mo;
            if (kglob < KP) {
                unsigned short tmp[8];
                #pragma unroll
                for (int i = 0; i < 8; ++i)
                    tmp[i] = (kglob + i < N_NODES) ? tb[c * 64 + mo + i] : (unsigned short)0;
                ushort4 v0, v1;
                v0.x = tmp[0]; v0.y = tmp[1]; v0.z = tmp[2]; v0.w = tmp[3];
                v1.x = tmp[4]; v1.y = tmp[5]; v1.z = tmp[6]; v1.w = tmp[7];
                *(ushort4*)(jkT + (size_t)c * KP + kglob)     = v0;
                *(ushort4*)(jkT + (size_t)c * KP + kglob + 4) = v1;
            }
        }
    }
}

// ---------------------------------------------------------------------------
// Full LSTM JK chain in one kernel: 4 steps, h-states in LDS, c in registers.
// BM=32 rows/block, grid 313. Final step fuses JK-mean + bn_in + ELU -> hpost.
// ---------------------------------------------------------------------------
__global__ __launch_bounds__(256) void lstm4_kernel(
    const float* __restrict__ jk0, const float* __restrict__ jk1,
    const unsigned short* __restrict__ wl,   // [2][512][256] bf16
    const float* __restrict__ bih0, const float* __restrict__ bhh0,
    const float* __restrict__ bih1, const float* __restrict__ bhh1,
    const float* __restrict__ bng, const float* __restrict__ bnb,
    const float* __restrict__ bnrm, const float* __restrict__ bnrv,
    float* __restrict__ hpost)
{
    __shared__ unsigned short sa[32 * 32];
    __shared__ unsigned short sb[512 * 32];
    __shared__ unsigned short hb[2][32][136];   // +8 pad
    const int tid = threadIdx.x, lane = tid & 63, w = tid >> 6;
    const int m0 = blockIdx.x * 32;
    const int arow = tid >> 2, agrp = tid & 3;  // A staging (tid<128)
    const int mg = min(m0 + arow, N_NODES - 1);

    f32x4 acc[2][8];
    float cst[2][2][4];

    auto zacc = [&] {
        #pragma unroll
        for (int i = 0; i < 2; ++i)
            #pragma unroll
            for (int j = 0; j < 8; ++j) acc[i][j] = (f32x4){0.f, 0.f, 0.f, 0.f};
    };
    auto stage_sb = [&](const unsigned short* wlayer, int k0) {
        #pragma unroll
        for (int t = 0; t < 8; ++t) {
            int gi = tid + t * 256, n = gi >> 2, grp = gi & 3;
            *(bf16x8*)(sb + n * 32 + ((grp ^ (n & 3)) << 3)) =
                *(const bf16x8*)(wlayer + (size_t)n * 256 + k0 + grp * 8);
        }
    };
    auto stage_sa = [&](const float* a, int k0) {
        if (tid < 128) {
            int kg = k0 + agrp * 8;
            const float* src = a + (size_t)mg * NH + kg;
            float4 u0 = *(const float4*)src, u1 = *(const float4*)(src + 4);
            float a8[8] = {u0.x, u0.y, u0.z, u0.w, u1.x, u1.y, u1.z, u1.w};
            *(bf16x8*)(sa + arow * 32 + ((agrp ^ (arow & 3)) << 3)) = cvt8(a8);
        }
    };
    auto av_sa = [&](int rb) {
        int row = rb * 16 + (lane & 15), g = lane >> 4;
        return *(const bf16x8*)(sa + row * 32 + ((g ^ (row & 3)) << 3));
    };
    auto av_hb = [&](int i, int rb, int kl) {
        int row = rb * 16 + (lane & 15), g = lane >> 4;
        return *(const bf16x8*)(&hb[i][row][kl + g * 8]);
    };
    auto mfma_all = [&](bf16x8 a0, bf16x8 a1) {
        #pragma unroll
        for (int gate = 0; gate < 4; ++gate)
            #pragma unroll
            for (int cb = 0; cb < 2; ++cb) {
                int col = gate * 128 + w * 32 + cb * 16 + (lane & 15);
                int g = lane >> 4;
                bf16x8 bv = *(const bf16x8*)(sb + col * 32 + ((g ^ (col & 3)) << 3));
                acc[0][gate * 2 + cb] =
                    __builtin_amdgcn_mfma_f32_16x16x32_bf16(a0, bv, acc[0][gate * 2 + cb], 0, 0, 0);
                acc[1][gate * 2 + cb] =
                    __builtin_amdgcn_mfma_f32_16x16x32_bf16(a1, bv, acc[1][gate * 2 + cb], 0, 0, 0);
            }
    };
    auto epi = [&](const float* bih, const float* bhh, bool hasc, int hdst, bool fin) {
        __syncthreads();
        #pragma unroll
        for (int cb = 0; cb < 2; ++cb) {
            int cg = w * 32 + cb * 16 + (lane & 15);
            float bi  = bih[cg]       + bhh[cg];
            float bf_ = bih[128 + cg] + bhh[128 + cg];
            float bgg = bih[256 + cg] + bhh[256 + cg];
            float bo  = bih[384 + cg] + bhh[384 + cg];
            float sc = 0.f, sh = 0.f;
            if (fin) {
                sc = bng[cg] / sqrtf(bnrv[cg] + BN_EPS);
                sh = bnb[cg] - bnrm[cg] * sc;
            }
            #pragma unroll
            for (int rb = 0; rb < 2; ++rb)
                #pragma unroll
                for (int reg = 0; reg < 4; ++reg) {
                    int lr = rb * 16 + (lane >> 4) * 4 + reg;
                    float zi = acc[rb][0 + cb][reg] + bi;
                    float zf = acc[rb][2 + cb][reg] + bf_;
                    float zg = acc[rb][4 + cb][reg] + bgg;
                    float zo = acc[rb][6 + cb][reg] + bo;
                    float cn = sigm(zi) * tanhf(zg);
                    if (hasc) cn += sigm(zf) * cst[rb][cb][reg];
                    cst[rb][cb][reg] = cn;
                    float hv = sigm(zo) * tanhf(cn);
                    if (fin) {
                        float hm = bf2f(hb[0][lr][cg]);     // h2_0
                        float t = 0.5f * (hm + hv);
                        t = t * sc + sh;
                        int m = m0 + lr;
                        if (m < N_NODES) hpost[(size_t)m * NH + cg] = t > 0.f ? t : expm1f(t);
                    } else {
                        hb[hdst][lr][cg] = f2bf(hv);
                    }
                }
        }
        __syncthreads();
    };

    // step0: L1 t0, A = jk0, K=128
    zacc();
    for (int k0 = 0; k0 < 128; k0 += 32) {
        __syncthreads();
        stage_sa(jk0, k0);
        stage_sb(wl, k0);
        __syncthreads();
        mfma_all(av_sa(0), av_sa(1));
    }
    epi(bih0, bhh0, false, 0, false);           // h1_0 -> hb0

    // step1: L1 t1, A = [jk1 | hb0], K=256
    zacc();
    for (int k0 = 0; k0 < 256; k0 += 32) {
        __syncthreads();
        if (k0 < 128) stage_sa(jk1, k0);
        stage_sb(wl, k0);
        __syncthreads();
        if (k0 < 128) mfma_all(av_sa(0), av_sa(1));
        else          mfma_all(av_hb(0, 0, k0 - 128), av_hb(0, 1, k0 - 128));
    }
    epi(bih0, bhh0, true, 1, false);            // h1_1 -> hb1

    // step2: L2 t0, A = hb0 (h1_0), K=128
    const unsigned short* wl1 = wl + 512 * 256;
    zacc();
    for (int k0 = 0; k0 < 128; k0 += 32) {
        __syncthreads();
        stage_sb(wl1, k0);
        __syncthreads();
        mfma_all(av_hb(0, 0, k0), av_hb(0, 1, k0));
    }
    epi(bih1, bhh1, false, 0, false);           // h2_0 -> hb0

    // step3: L2 t1, A = [hb1 | hb0] = [h1_1 | h2_0], K=256, FINAL
    zacc();
    for (int k0 = 0; k0 < 256; k0 += 32) {
        __syncthreads();
        stage_sb(wl1, k0);
        __syncthreads();
        if (k0 < 128) mfma_all(av_hb(1, 0, k0), av_hb(1, 1, k0));
        else          mfma_all(av_hb(0, 0, k0 - 128), av_hb(0, 1, k0 - 128));
    }
    epi(bih1, bhh1, true, -1, true);            // hpost out
}

// ---------------------------------------------------------------------------
// Epilogue: e=elu(bn(embed@W_emb^T)) -> LDS; hfc=elu(bn([hpost|e]@W_fc^T))
// -> LDS; out = log_softmax(hfc@W_out^T + b). BM=64, grid MT.
// ---------------------------------------------------------------------------
__global__ __launch_bounds__(256) void epilogue_kernel(
    const float* __restrict__ embed,
    const float* __restrict__ W_emb, const float* __restrict__ b_emb,
    const float* __restrict__ bn_e_g, const float* __restrict__ bn_e_b,
    const float* __restrict__ bn_e_rm, const float* __restrict__ bn_e_rv,
    const float* __restrict__ hpost,
    const float* __restrict__ W_fc, const float* __restrict__ b_fc,
    const float* __restrict__ bn_f_g, const float* __restrict__ bn_f_b,
    const float* __restrict__ bn_f_rm, const float* __restrict__ bn_f_rv,
    const float* __restrict__ W_out, const float* __restrict__ b_out,
    float* __restrict__ out)
{
    __shared__ unsigned short sa[64 * 32];
    __shared__ unsigned short sb[192 * 32];
    __shared__ unsigned short ebuf[64][72];
    __shared__ float fbuf[64][204];
    const int tid = threadIdx.x, lane = tid & 63, w = tid >> 6;
    const int m0 = blockIdx.x * 64;
    const int arow = tid >> 2, agrp = tid & 3;
    const int mg = min(m0 + arow, N_NODES - 1);
    const int g = lane >> 4;

    // ---- phase E ----
    f32x4 aE[4];
    #pragma unroll
    for (int j = 0; j < 4; ++j) aE[j] = (f32x4){0.f, 0.f, 0.f, 0.f};
    for (int k0 = 0; k0 < NFE; k0 += 32) {
        float a8[8], b8[8];
        {
            const float* s = embed + (size_t)mg * NFE + k0 + agrp * 8;
            float4 u0 = *(const float4*)s, u1 = *(const float4*)(s + 4);
            a8[0]=u0.x; a8[1]=u0.y; a8[2]=u0.z; a8[3]=u0.w;
            a8[4]=u1.x; a8[5]=u1.y; a8[6]=u1.z; a8[7]=u1.w;
        }
        {
            const float* s = W_emb + (size_t)arow * NFE + k0 + agrp * 8;  // arow<64=NHE
            float4 u0 = *(const float4*)s, u1 = *(const float4*)(s + 4);
            b8[0]=u0.x; b8[1]=u0.y; b8[2]=u0.z; b8[3]=u0.w;
            b8[4]=u1.x; b8[5]=u1.y; b8[6]=u1.z; b8[7]=u1.w;
        }
        __syncthreads();
        *(bf16x8*)(sa + arow * 32 + ((agrp ^ (arow & 3)) << 3)) = cvt8(a8);
        *(bf16x8*)(sb + arow * 32 + ((agrp ^ (arow & 3)) << 3)) = cvt8(b8);
        __syncthreads();
        bf16x8 av;
        { int row = w * 16 + (lane & 15);
          av = *(const bf16x8*)(sa + row * 32 + ((g ^ (row & 3)) << 3)); }
        #pragma unroll
        for (int cb = 0; cb < 4; ++cb) {
            int col = cb * 16 + (lane & 15);
            bf16x8 bv = *(const bf16x8*)(sb + col * 32 + ((g ^ (col & 3)) << 3));
            aE[cb] = __builtin_amdgcn_mfma_f32_16x16x32_bf16(av, bv, aE[cb], 0, 0, 0);
        }
    }
    #pragma unroll
    for (int cb = 0; cb < 4; ++cb) {
        int col = cb * 16 + (lane & 15);
        float sc = bn_e_g[col] / sqrtf(bn_e_rv[col] + BN_EPS);
        float sh = bn_e_b[col] - bn_e_rm[col] * sc;
        float bb = b_emb[col];
        #pragma unroll
        for (int reg = 0; reg < 4; ++reg) {
            int row = w * 16 + (lane >> 4) * 4 + reg;
            float t = (aE[cb][reg] + bb) * sc + sh;
            ebuf[row][col] = f2bf(t > 0.f ? t : expm1f(t));
        }
    }
    __syncthreads();

    // ---- phase F ----
    f32x4 aF[4][3];
    #pragma unroll
    for (int i = 0; i < 4; ++i)
        #pragma unroll
        for (int j = 0; j < 3; ++j) aF[i][j] = (f32x4){0.f, 0.f, 0.f, 0.f};
    for (int k0 = 0; k0 < DCAT; k0 += 32) {
        const bool gl = (k0 < 128);
        float b8[3][8];
        #pragma unroll
        for (int t = 0; t < 3; ++t) {
            int gi = tid + t * 256, n = gi >> 2, grp = gi & 3;
            const float* s = W_fc + (size_t)n * DCAT + k0 + grp * 8;
            float4 u0 = *(const float4*)s, u1 = *(const float4*)(s + 4);
            b8[t][0]=u0.x; b8[t][1]=u0.y; b8[t][2]=u0.z; b8[t][3]=u0.w;
            b8[t][4]=u1.x; b8[t][5]=u1.y; b8[t][6]=u1.z; b8[t][7]=u1.w;
        }
        float a8[8];
        if (gl) {
            const float* s = hpost + (size_t)mg * NH + k0 + agrp * 8;
            float4 u0 = *(const float4*)s, u1 = *(const float4*)(s + 4);
            a8[0]=u0.x; a8[1]=u0.y; a8[2]=u0.z; a8[3]=u0.w;
            a8[4]=u1.x; a8[5]=u1.y; a8[6]=u1.z; a8[7]=u1.w;
        }
        __syncthreads();
        if (gl) *(bf16x8*)(sa + arow * 32 + ((agrp ^ (arow & 3)) << 3)) = cvt8(a8);
        #pragma unroll
        for (int t = 0; t < 3; ++t) {
            int gi = tid + t * 256, n = gi >> 2, grp = gi & 3;
            *(bf16x8*)(sb + n * 32 + ((grp ^ (n & 3)) << 3)) = cvt8(b8[t]);
        }
        __syncthreads();
        #pragma unroll
        for (int rf = 0; rf < 4; ++rf) {
            int row = rf * 16 + (lane & 15);
            bf16x8 av = gl ? *(const bf16x8*)(sa + row * 32 + ((g ^ (row & 3)) << 3))
                           : *(const bf16x8*)(&ebuf[row][(k0 - 128) + g * 8]);
            #pragma unroll
            for (int cf = 0; cf < 3; ++cf) {
                int col = w * 48 + cf * 16 + (lane & 15);
                bf16x8 bv = *(const bf16x8*)(sb + col * 32 + ((g ^ (col & 3)) << 3));
                aF[rf][cf] = __builtin_amdgcn_mfma_f32_16x16x32_bf16(av, bv, aF[rf][cf], 0, 0, 0);
            }
        }
    }
    #pragma unroll
    for (int cf = 0; cf < 3; ++cf) {
        int col = w * 48 + cf * 16 + (lane & 15);
        float sc = bn_f_g[col] / sqrtf(bn_f_rv[col] + BN_EPS);
        float sh = bn_f_b[col] - bn_f_rm[col] * sc;
        float bb = b_fc[col];
        #pragma unroll
        for (int rf = 0; rf < 4; ++rf)
            #pragma unroll
            for (int reg = 0; reg < 4; ++reg) {
                int row = rf * 16 + (lane >> 4) * 4 + reg;
                float t = (aF[rf][cf][reg] + bb) * sc + sh;
                fbuf[row][col] = t > 0.f ? t : expm1f(t);
            }
    }
    __syncthreads();

    // ---- phase O ----
    f32x4 aO[2];
    aO[0] = (f32x4){0.f, 0.f, 0.f, 0.f};
    aO[1] = (f32x4){0.f, 0.f, 0.f, 0.f};
    for (int k0 = 0; k0 < DCAT; k0 += 32) {
        float b8[8];
        const bool act = tid < 128;                       // 32 out-cols x 4 granules
        if (act) {
            if (arow < NOUT) {
                const float* s = W_out + (size_t)arow * DCAT + k0 + agrp * 8;
                float4 u0 = *(const float4*)s, u1 = *(const float4*)(s + 4);
                b8[0]=u0.x; b8[1]=u0.y; b8[2]=u0.z; b8[3]=u0.w;
                b8[4]=u1.x; b8[5]=u1.y; b8[6]=u1.z; b8[7]=u1.w;
            } else {
                #pragma unroll
                for (int i = 0; i < 8; ++i) b8[i] = 0.f;
            }
        }
        __syncthreads();
        if (act) *(bf16x8*)(sb + arow * 32 + ((agrp ^ (arow & 3)) << 3)) = cvt8(b8);
        __syncthreads();
        int row = w * 16 + (lane & 15);
        float4 f0 = *(const float4*)(&fbuf[row][k0 + g * 8]);
        float4 f1 = *(const float4*)(&fbuf[row][k0 + g * 8 + 4]);
        float f8[8] = {f0.x, f0.y, f0.z, f0.w, f1.x, f1.y, f1.z, f1.w};
        bf16x8 av = cvt8(f8);
        #pragma unroll
        for (int cf = 0; cf < 2; ++cf) {
            int col = cf * 16 + (lane & 15);
            bf16x8 bv = *(const bf16x8*)(sb + col * 32 + ((g ^ (col & 3)) << 3));
            aO[cf] = __builtin_amdgcn_mfma_f32_16x16x32_bf16(av, bv, aO[cf], 0, 0, 0);
        }
    }
    const int c0i = lane & 15, c1i = 16 + (lane & 15);
    const bool v1 = c1i < NOUT;
    #pragma unroll
    for (int reg = 0; reg < 4; ++reg) {
        int row = w * 16 + (lane >> 4) * 4 + reg;
        int m = m0 + row;
        float l0 = aO[0][reg] + b_out[c0i];
        float l1 = v1 ? (aO[1][reg] + b_out[c1i]) : -INFINITY;
        float mx = fmaxf(l0, l1);
        #pragma unroll
        for (int msk = 1; msk < 16; msk <<= 1) mx = fmaxf(mx, __shfl_xor(mx, msk));
        float s = expf(l0 - mx) + (v1 ? expf(l1 - mx) : 0.f);
        #pragma unroll
        for (int msk = 1; msk < 16; msk <<= 1) s += __shfl_xor(s, msk);
        float lse = mx + logf(s);
        if (m < N_NODES) {
            out[(size_t)m * NOUT + c0i] = l0 - lse;
            if (v1) out[(size_t)m * NOUT + c1i] = l1 - lse;
        }
    }
}

// ---------------------------------------------------------------------------
extern "C" void kernel_launch(void* const* d_in, const int* in_sizes, int n_in,
                              void* d_out, int out_size, void* d_ws, size_t ws_size,
                              hipStream_t stream)
{
    const float* x       = (const float*)d_in[0];
    const float* embed   = (const float*)d_in[1];
    const float* adj     = (const float*)d_in[2];
    const float* W_in    = (const float*)d_in[3];
    const float* b_in    = (const float*)d_in[4];
    const float* bn_in_g = (const float*)d_in[5];
    const float* bn_in_b = (const float*)d_in[6];
    const float* bn_in_rm= (const float*)d_in[7];
    const float* bn_in_rv= (const float*)d_in[8];
    const float* W_gs    = (const float*)d_in[9];
    const float* b_gs    = (const float*)d_in[10];
    const float* Wih0    = (const float*)d_in[11];
    const float* Whh0    = (const float*)d_in[12];
    const float* bih0    = (const float*)d_in[13];
    const float* bhh0    = (const float*)d_in[14];
    const float* Wih1    = (const float*)d_in[15];
    const float* Whh1    = (const float*)d_in[16];
    const float* bih1    = (const float*)d_in[17];
    const float* bhh1    = (const float*)d_in[18];
    const float* W_emb   = (const float*)d_in[19];
    const float* b_emb   = (const float*)d_in[20];
    const float* bn_e_g  = (const float*)d_in[21];
    const float* bn_e_b  = (const float*)d_in[22];
    const float* bn_e_rm = (const float*)d_in[23];
    const float* bn_e_rv = (const float*)d_in[24];
    const float* W_fc    = (const float*)d_in[25];
    const float* b_fc    = (const float*)d_in[26];
    const float* bn_f_g  = (const float*)d_in[27];
    const float* bn_f_b  = (const float*)d_in[28];
    const float* bn_f_rm = (const float*)d_in[29];
    const float* bn_f_rv = (const float*)d_in[30];
    const float* W_out   = (const float*)d_in[31];
    const float* b_out   = (const float*)d_in[32];
    float* outp = (float*)d_out;

    const size_t HB = (size_t)N_NODES * NH * sizeof(float);
    char* wp = (char*)d_ws;
    auto carve = [&](size_t bytes) {
        void* p = (void*)wp;
        wp += (bytes + 1023) & ~(size_t)1023;
        return p;
    };
    void* partRaw = carve((size_t)NSPLIT * MPAD * NH * 2);     // 41.2 MB (bf16 view)
    unsigned short* partB = (unsigned short*)partRaw;
    float* partF = (float*)partRaw;                             // xw f32 view (4 chunks fit)
    float* part_s= (float*)carve((size_t)NSPLIT * MPAD * sizeof(float));
    unsigned short* adjb = (unsigned short*)carve((size_t)N_NODES * KP * 2); // 200.3 MB
    float* h_in  = (float*)carve(HB);
    float* jk0   = (float*)carve(HB);
    float* jk1   = (float*)carve(HB);
    float* hpost = (float*)carve(HB);
    unsigned short* hT  = (unsigned short*)carve((size_t)NH * KP * 2);
    unsigned short* wl  = (unsigned short*)carve((size_t)2 * 512 * 256 * 2);
    unsigned short* wgb = (unsigned short*)carve((size_t)2 * 128 * 256 * 2);
    if ((size_t)(wp - (char*)d_ws) > ws_size) return;

    const dim3 blk(256);

    // 1. h_in = elu(bn_in(x @ W_in.T + b_in)); also h_inT; weight packing folded in
    xw_mfma_kernel<<<dim3(MT, NSPLX), blk, 0, stream>>>(x, W_in, partF,
                                                        Wih0, Whh0, Wih1, Whh1, W_gs,
                                                        wl, wgb);
    xw_reduce_kernel<<<1250, blk, 0, stream>>>(partF, b_in, bn_in_g, bn_in_b,
                                               bn_in_rm, bn_in_rv, h_in, hT);

    // 2. GraphSAGE layer 0: read f32 adj, write bf16 adjb copy + rowsums
    adjmm_kernel<0, 0><<<dim3(MT, NSPLIT), blk, 0, stream>>>(adj, adjb, hT, partB, part_s);
    gs_fused_kernel<true><<<MT, blk, 0, stream>>>(h_in, partB, part_s, wgb, b_gs, jk0, hT);

    // 3. GraphSAGE layer 1: read bf16 adjb (L3-resident), REVERSED order
    adjmm_kernel<1, 1><<<dim3(MT, NSPLIT), blk, 0, stream>>>(adj, adjb, hT, partB, part_s);
    gs_fused_kernel<false><<<MT, blk, 0, stream>>>(jk0, partB, part_s, wgb + 128 * 256,
                                                   b_gs + 128, jk1, nullptr);

    // 4. LSTM JK chain (4 steps in one kernel) + JK-mean + bn + elu
    lstm4_kernel<<<313, blk, 0, stream>>>(jk0, jk1, wl, bih0, bhh0, bih1, bhh1,
                                          bn_in_g, bn_in_b, bn_in_rm, bn_in_rv, hpost);

    // 5. emb + fc + log_softmax fused epilogue
    epilogue_kernel<<<MT, blk, 0, stream>>>(embed, W_emb, b_emb,
                                            bn_e_g, bn_e_b, bn_e_rm, bn_e_rv,
                                            hpost, W_fc, b_fc,
                                            bn_f_g, bn_f_b, bn_f_rm, bn_f_rv,
                                            W_out, b_out, outp);
}

// Round 10
// 447.398 us; speedup vs baseline: 1.1052x; 1.1052x over previous
//
#include <hip/hip_runtime.h>
#include <hip/hip_bf16.h>
#include <math.h>

#define N_NODES 10000
#define NFEAT   2000
#define NFE     256
#define NH      128
#define NHE     64
#define NOUT    20
#define DCAT    192
#define BN_EPS  1e-5f

#define KP      10016        // padded K for transposed activations
#define KSTEPS  313
#define MT      157          // 64-row m-tiles
#define NSPLIT  16           // adjmm split-K
#define KC      20
#define NSPLX   4            // xw split-K
#define MPAD    10048

typedef __attribute__((ext_vector_type(8))) short  bf16x8;
typedef __attribute__((ext_vector_type(4))) float  f32x4;

__device__ __forceinline__ float sigm(float x) { return 1.0f / (1.0f + expf(-x)); }

__device__ __forceinline__ unsigned short f2bf(float x) {
    union { __hip_bfloat16 h; unsigned short u; } c;
    c.h = __float2bfloat16(x);
    return c.u;
}

__device__ __forceinline__ float bf2f(unsigned short u) {
    union { float f; unsigned int i; } c;
    c.i = ((unsigned int)u) << 16;
    return c.f;
}

__device__ __forceinline__ bf16x8 cvt8(const float* v) {
    bf16x8 r;
    #pragma unroll
    for (int i = 0; i < 8; ++i) r[i] = (short)f2bf(v[i]);
    return r;
}

// ---------------------------------------------------------------------------
// adjmm split-K, ping-pong LDS, loads fully overlapped (rs after MFMA).
// part[chunk] (bf16) = adj @ hT^T ; part_s rowsum partials.
// REV=1 reverses block->tile mapping so pass 2 starts on the L3-resident
// tail of adj left by pass 1 (LRU streaming reuse).
// Coalesced part store via LDS bounce (reuses sb after the K-loop).
// ---------------------------------------------------------------------------
template<int REV>
__global__ __launch_bounds__(256) void adjmm_kernel(const float* __restrict__ adj,
                                                    const unsigned short* __restrict__ hT,
                                                    unsigned short* __restrict__ part,
                                                    float* __restrict__ part_s)
{
    __shared__ unsigned short sa[2][64 * 32];
    __shared__ unsigned short sb[2][128 * 32];
    const int tid  = threadIdx.x;
    const int lane = tid & 63, w = tid >> 6;
    const int bx   = REV ? (int)gridDim.x - 1 - (int)blockIdx.x : (int)blockIdx.x;
    const int by   = REV ? (int)gridDim.y - 1 - (int)blockIdx.y : (int)blockIdx.y;
    const int m0   = bx * 64;
    const int ks0  = by * KC;
    const int ks1  = min(ks0 + KC, KSTEPS);
    const int r0   = (w & 1) * 32;
    const int c0   = (w >> 1) * 64;

    const int arow = tid >> 2, agrp = tid & 3;
    const size_t abase = (size_t)min(m0 + arow, N_NODES - 1) * N_NODES;
    const int bcol = tid >> 1, bg0 = (tid & 1) * 2;

    const int asoff  = arow * 32 + ((agrp ^ (arow & 3)) << 3);
    const int bsoff0 = bcol * 32 + (((bg0 + 0) ^ (bcol & 3)) << 3);
    const int bsoff1 = bcol * 32 + (((bg0 + 1) ^ (bcol & 3)) << 3);

    float rs = 0.f;
    f32x4 acc[2][4];
    #pragma unroll
    for (int i = 0; i < 2; ++i)
        #pragma unroll
        for (int j = 0; j < 4; ++j) acc[i][j] = (f32x4){0.f, 0.f, 0.f, 0.f};

    float av8[8];
    bf16x8 vb0, vb1;
    auto load_step = [&](int ks) {            // loads only — no VALU use
        const int k0 = ks * 32;
        const int kg = k0 + agrp * 8;
        if (kg + 8 <= N_NODES) {
            float4 u0 = *(const float4*)(adj + abase + kg);
            float4 u1 = *(const float4*)(adj + abase + kg + 4);
            av8[0] = u0.x; av8[1] = u0.y; av8[2] = u0.z; av8[3] = u0.w;
            av8[4] = u1.x; av8[5] = u1.y; av8[6] = u1.z; av8[7] = u1.w;
        } else {
            #pragma unroll
            for (int i = 0; i < 8; ++i) av8[i] = 0.f;
        }
        vb0 = *(const bf16x8*)(hT + (size_t)bcol * KP + k0 + bg0 * 8);
        vb1 = *(const bf16x8*)(hT + (size_t)bcol * KP + k0 + (bg0 + 1) * 8);
    };
    auto write_step = [&](int p) {            // first use of loads: after MFMA
        #pragma unroll
        for (int i = 0; i < 8; ++i) rs += av8[i];
        *(bf16x8*)(sa[p] + asoff)  = cvt8(av8);
        *(bf16x8*)(sb[p] + bsoff0) = vb0;
        *(bf16x8*)(sb[p] + bsoff1) = vb1;
    };

    load_step(ks0);
    write_step(0);

    for (int ks = ks0; ks < ks1; ++ks) {
        const int p = (ks - ks0) & 1;
        const bool more = (ks + 1 < ks1);
        if (more) load_step(ks + 1);
        __syncthreads();
        bf16x8 av[2], bv[4];
        #pragma unroll
        for (int rb = 0; rb < 2; ++rb) {
            int row = r0 + rb * 16 + (lane & 15);
            int g   = lane >> 4;
            av[rb] = *(const bf16x8*)(sa[p] + row * 32 + ((g ^ (row & 3)) << 3));
        }
        #pragma unroll
        for (int cb = 0; cb < 4; ++cb) {
            int col = c0 + cb * 16 + (lane & 15);
            int g   = lane >> 4;
            bv[cb] = *(const bf16x8*)(sb[p] + col * 32 + ((g ^ (col & 3)) << 3));
        }
        #pragma unroll
        for (int rb = 0; rb < 2; ++rb)
            #pragma unroll
            for (int cb = 0; cb < 4; ++cb)
                acc[rb][cb] = __builtin_amdgcn_mfma_f32_16x16x32_bf16(av[rb], bv[cb],
                                                                      acc[rb][cb], 0, 0, 0);
        if (more) write_step(p ^ 1);
    }

    rs += __shfl_xor(rs, 1);
    rs += __shfl_xor(rs, 2);
    if ((tid & 3) == 0) part_s[(size_t)by * MPAD + m0 + arow] = rs;

    // coalesced part store: acc -> LDS bounce (reuse sb: 2*128*32 = 64x128) -> 16B stores
    unsigned short* bounce = (unsigned short*)sb;
    __syncthreads();
    #pragma unroll
    for (int rb = 0; rb < 2; ++rb)
        #pragma unroll
        for (int cb = 0; cb < 4; ++cb) {
            int lrb = r0 + rb * 16 + (lane >> 4) * 4;
            int col = c0 + cb * 16 + (lane & 15);
            #pragma unroll
            for (int reg = 0; reg < 4; ++reg)
                bounce[(lrb + reg) * 128 + col] = f2bf(acc[rb][cb][reg]);
        }
    __syncthreads();
    unsigned short* pout = part + (size_t)by * MPAD * NH + (size_t)m0 * NH;
    #pragma unroll
    for (int t = 0; t < 4; ++t) {
        int flat = tid + t * 256;
        *(bf16x8*)(pout + flat * 8) = *(const bf16x8*)(bounce + flat * 8);
    }
}

// ---------------------------------------------------------------------------
// x @ W_in.T split-K (4 chunks of 16 K-steps), pipelined ping-pong.
// by==0 blocks additionally pack LSTM/GS weights to bf16 (wl, wgb) at the end.
// ---------------------------------------------------------------------------
__global__ __launch_bounds__(256) void xw_mfma_kernel(const float* __restrict__ x,
                                                      const float* __restrict__ Wn,
                                                      float* __restrict__ part,
                                                      const float* __restrict__ Wih0,
                                                      const float* __restrict__ Whh0,
                                                      const float* __restrict__ Wih1,
                                                      const float* __restrict__ Whh1,
                                                      const float* __restrict__ Wgs,
                                                      unsigned short* __restrict__ wl,
                                                      unsigned short* __restrict__ wgb)
{
    __shared__ unsigned short sa[2][64 * 32];
    __shared__ unsigned short sb[2][128 * 32];
    const int tid  = threadIdx.x;
    const int lane = tid & 63, w = tid >> 6;
    const int m0   = blockIdx.x * 64;
    const int TOT  = (NFEAT + 31) / 32;                 // 63
    const int s0   = blockIdx.y * 16;
    const int s1   = min(s0 + 16, TOT);
    const int r0   = (w & 1) * 32;
    const int c0   = (w >> 1) * 64;

    const int arow = tid >> 2, agrp = tid & 3;
    const size_t abase = (size_t)min(m0 + arow, N_NODES - 1) * NFEAT;
    const int asoff = arow * 32 + ((agrp ^ (arow & 3)) << 3);
    int bn_[2], bgrp_[2], bsoff_[2];
    #pragma unroll
    for (int t = 0; t < 2; ++t) {
        int gi = tid + t * 256;
        bn_[t] = gi >> 2; bgrp_[t] = gi & 3;
        bsoff_[t] = bn_[t] * 32 + ((bgrp_[t] ^ (bn_[t] & 3)) << 3);
    }

    f32x4 acc[2][4];
    #pragma unroll
    for (int i = 0; i < 2; ++i)
        #pragma unroll
        for (int j = 0; j < 4; ++j) acc[i][j] = (f32x4){0.f, 0.f, 0.f, 0.f};

    float av8[8], bv8[2][8];
    auto load_step = [&](int ks) {
        const int k0 = ks * 32;
        {
            const int kg = k0 + agrp * 8;
            if (kg + 8 <= NFEAT) {
                float4 u0 = *(const float4*)(x + abase + kg);
                float4 u1 = *(const float4*)(x + abase + kg + 4);
                av8[0]=u0.x; av8[1]=u0.y; av8[2]=u0.z; av8[3]=u0.w;
                av8[4]=u1.x; av8[5]=u1.y; av8[6]=u1.z; av8[7]=u1.w;
            } else {
                #pragma unroll
                for (int i = 0; i < 8; ++i) av8[i] = 0.f;
            }
        }
        #pragma unroll
        for (int t = 0; t < 2; ++t) {
            int kg = k0 + bgrp_[t] * 8;
            if (kg + 8 <= NFEAT) {
                float4 u0 = *(const float4*)(Wn + (size_t)bn_[t] * NFEAT + kg);
                float4 u1 = *(const float4*)(Wn + (size_t)bn_[t] * NFEAT + kg + 4);
                bv8[t][0]=u0.x; bv8[t][1]=u0.y; bv8[t][2]=u0.z; bv8[t][3]=u0.w;
                bv8[t][4]=u1.x; bv8[t][5]=u1.y; bv8[t][6]=u1.z; bv8[t][7]=u1.w;
            } else {
                #pragma unroll
                for (int i = 0; i < 8; ++i) bv8[t][i] = 0.f;
            }
        }
    };
    auto write_step = [&](int p) {
        *(bf16x8*)(sa[p] + asoff) = cvt8(av8);
        #pragma unroll
        for (int t = 0; t < 2; ++t)
            *(bf16x8*)(sb[p] + bsoff_[t]) = cvt8(bv8[t]);
    };

    load_step(s0);
    write_step(0);

    for (int ks = s0; ks < s1; ++ks) {
        const int p = (ks - s0) & 1;
        const bool more = (ks + 1 < s1);
        if (more) load_step(ks + 1);
        __syncthreads();
        bf16x8 av[2], bv[4];
        #pragma unroll
        for (int rb = 0; rb < 2; ++rb) {
            int row = r0 + rb * 16 + (lane & 15);
            int g   = lane >> 4;
            av[rb] = *(const bf16x8*)(sa[p] + row * 32 + ((g ^ (row & 3)) << 3));
        }
        #pragma unroll
        for (int cb = 0; cb < 4; ++cb) {
            int col = c0 + cb * 16 + (lane & 15);
            int g   = lane >> 4;
            bv[cb] = *(const bf16x8*)(sb[p] + col * 32 + ((g ^ (col & 3)) << 3));
        }
        #pragma unroll
        for (int rb = 0; rb < 2; ++rb)
            #pragma unroll
            for (int cb = 0; cb < 4; ++cb)
                acc[rb][cb] = __builtin_amdgcn_mfma_f32_16x16x32_bf16(av[rb], bv[cb],
                                                                      acc[rb][cb], 0, 0, 0);
        if (more) write_step(p ^ 1);
    }
    float* pout = part + (size_t)blockIdx.y * MPAD * NH;
    #pragma unroll
    for (int rb = 0; rb < 2; ++rb)
        #pragma unroll
        for (int cb = 0; cb < 4; ++cb) {
            int rowb = m0 + r0 + rb * 16 + (lane >> 4) * 4;
            int col  = c0 + cb * 16 + (lane & 15);
            #pragma unroll
            for (int reg = 0; reg < 4; ++reg)
                pout[(size_t)(rowb + reg) * NH + col] = acc[rb][cb][reg];
        }

    // fold-in: pack weights to bf16 (consumers run after adjmm0/gs0)
    if (blockIdx.y == 0) {
        const int total = 262144 + 65536;
        for (int i = blockIdx.x * 256 + tid; i < total; i += MT * 256) {
            if (i < 262144) {
                int l = i >> 17, rem = i & 131071;
                int n = rem >> 8, k = rem & 255;
                const float* src;
                if (l == 0) src = (k < 128) ? (Wih0 + n * 128 + k) : (Whh0 + n * 128 + (k - 128));
                else        src = (k < 128) ? (Wih1 + n * 128 + k) : (Whh1 + n * 128 + (k - 128));
                wl[i] = f2bf(*src);
            } else {
                int j = i - 262144;
                wgb[j] = f2bf(Wgs[j]);
            }
        }
    }
}

// ---------------------------------------------------------------------------
// h_in = elu(bn_in(sum part + b_in)); also writes h_inT bf16 [128][KP] + pad
// ---------------------------------------------------------------------------
__global__ __launch_bounds__(256) void xw_reduce_kernel(const float* __restrict__ part,
                                                        const float* __restrict__ bias,
                                                        const float* __restrict__ g,
                                                        const float* __restrict__ bb,
                                                        const float* __restrict__ rm,
                                                        const float* __restrict__ rv,
                                                        float* __restrict__ h,
                                                        unsigned short* __restrict__ hT)
{
    __shared__ unsigned short tb[128][8];
    const int tid = threadIdx.x;
    int idx = blockIdx.x * 256 + tid;
    const int c4 = (tid & 31) * 4;
    const int lr = tid >> 5;                       // 0..7
    const int m0g = blockIdx.x * 8;
    const size_t ch = (size_t)MPAD * NH / 4;
    const float4* p = (const float4*)part;
    float a[4] = {0.f, 0.f, 0.f, 0.f};
    #pragma unroll
    for (int c = 0; c < NSPLX; ++c) {
        float4 v = p[c * ch + idx];
        a[0] += v.x; a[1] += v.y; a[2] += v.z; a[3] += v.w;
    }
    float o[4];
    #pragma unroll
    for (int j = 0; j < 4; ++j) {
        int c = c4 + j;
        float sc = g[c] / sqrtf(rv[c] + BN_EPS);
        float t = (a[j] + bias[c] - rm[c]) * sc + bb[c];
        o[j] = t > 0.f ? t : expm1f(t);
        tb[c][lr] = f2bf(o[j]);
    }
    float4 ov; ov.x = o[0]; ov.y = o[1]; ov.z = o[2]; ov.w = o[3];
    *(float4*)(h + (size_t)idx * 4) = ov;
    __syncthreads();
    if (tid < 128) {
        ushort4 v0, v1;
        v0.x = tb[tid][0]; v0.y = tb[tid][1]; v0.z = tb[tid][2]; v0.w = tb[tid][3];
        v1.x = tb[tid][4]; v1.y = tb[tid][5]; v1.z = tb[tid][6]; v1.w = tb[tid][7];
        *(ushort4*)(hT + (size_t)tid * KP + m0g)     = v0;
        *(ushort4*)(hT + (size_t)tid * KP + m0g + 4) = v1;
        if (blockIdx.x == 0) {                     // zero the K-pad [10000,10016)
            ushort4 zz; zz.x = zz.y = zz.z = zz.w = 0;
            #pragma unroll
            for (int q = 0; q < 4; ++q)
                *(ushort4*)(hT + (size_t)tid * KP + 10000 + q * 4) = zz;
        }
    }
}

// ---------------------------------------------------------------------------
// GraphSAGE fused (+nreduce): A = [h | (sum_c bf16 part)/rowsum];
// jk = rownorm(relu(A@Wg^T + bg)); opt. jkT bf16. BM=64, K=256, grid MT.
// ---------------------------------------------------------------------------
template<bool WRITE_T>
__global__ __launch_bounds__(256) void gs_fused_kernel(const float* __restrict__ h,
                                                       const unsigned short* __restrict__ part,
                                                       const float* __restrict__ part_s,
                                                       const unsigned short* __restrict__ Wg,
                                                       const float* __restrict__ bg,
                                                       float* __restrict__ jk,
                                                       unsigned short* __restrict__ jkT)
{
    __shared__ unsigned short sa[64 * 32];
    __shared__ unsigned short sb[128 * 32];
    __shared__ float ssq_l[64][2];
    __shared__ unsigned short tb[WRITE_T ? 128 * 64 : 1];
    const int tid  = threadIdx.x;
    const int lane = tid & 63, w = tid >> 6;
    const int m0   = blockIdx.x * 64;
    const int r0   = (w & 1) * 32;
    const int c0   = (w >> 1) * 64;
    const int arow = tid >> 2, agrp = tid & 3;
    const int mg   = min(m0 + arow, N_NODES - 1);

    float inv;
    {
        float s = 0.f;
        #pragma unroll
        for (int c = 0; c < NSPLIT; ++c) s += part_s[(size_t)c * MPAD + mg];
        inv = 1.0f / s;
    }

    f32x4 acc[2][4];
    #pragma unroll
    for (int i = 0; i < 2; ++i)
        #pragma unroll
        for (int j = 0; j < 4; ++j) acc[i][j] = (f32x4){0.f, 0.f, 0.f, 0.f};

    for (int k0 = 0; k0 < 256; k0 += 32) {
        const int kg = k0 + agrp * 8;
        float a8[8];
        if (kg < 128) {
            const float* asrc = h + (size_t)mg * NH + kg;
            float4 u0 = *(const float4*)asrc;
            float4 u1 = *(const float4*)(asrc + 4);
            a8[0]=u0.x; a8[1]=u0.y; a8[2]=u0.z; a8[3]=u0.w;
            a8[4]=u1.x; a8[5]=u1.y; a8[6]=u1.z; a8[7]=u1.w;
        } else {
            const int cc = kg - 128;
            float s[8] = {0.f,0.f,0.f,0.f,0.f,0.f,0.f,0.f};
            #pragma unroll
            for (int c = 0; c < NSPLIT; ++c) {
                bf16x8 v = *(const bf16x8*)(part + (size_t)c * MPAD * NH + (size_t)mg * NH + cc);
                #pragma unroll
                for (int i = 0; i < 8; ++i) s[i] += bf2f((unsigned short)v[i]);
            }
            #pragma unroll
            for (int i = 0; i < 8; ++i) a8[i] = s[i] * inv;
        }
        bf16x8 b8[2];
        #pragma unroll
        for (int t = 0; t < 2; ++t) {
            int gi = tid + t * 256;
            int n = gi >> 2, grp = gi & 3;
            b8[t] = *(const bf16x8*)(Wg + (size_t)n * 256 + k0 + grp * 8);
        }
        __syncthreads();
        *(bf16x8*)(sa + arow * 32 + ((agrp ^ (arow & 3)) << 3)) = cvt8(a8);
        #pragma unroll
        for (int t = 0; t < 2; ++t) {
            int gi = tid + t * 256;
            int n = gi >> 2, grp = gi & 3;
            *(bf16x8*)(sb + n * 32 + ((grp ^ (n & 3)) << 3)) = b8[t];
        }
        __syncthreads();
        bf16x8 av[2], bv[4];
        #pragma unroll
        for (int rb = 0; rb < 2; ++rb) {
            int row = r0 + rb * 16 + (lane & 15);
            int g   = lane >> 4;
            av[rb] = *(const bf16x8*)(sa + row * 32 + ((g ^ (row & 3)) << 3));
        }
        #pragma unroll
        for (int cb = 0; cb < 4; ++cb) {
            int col = c0 + cb * 16 + (lane & 15);
            int g   = lane >> 4;
            bv[cb] = *(const bf16x8*)(sb + col * 32 + ((g ^ (col & 3)) << 3));
        }
        #pragma unroll
        for (int rb = 0; rb < 2; ++rb)
            #pragma unroll
            for (int cb = 0; cb < 4; ++cb)
                acc[rb][cb] = __builtin_amdgcn_mfma_f32_16x16x32_bf16(av[rb], bv[cb],
                                                                      acc[rb][cb], 0, 0, 0);
    }

    float vv[2][4][4];
    float ps[2][4] = {};
    #pragma unroll
    for (int rb = 0; rb < 2; ++rb)
        #pragma unroll
        for (int cb = 0; cb < 4; ++cb) {
            int colg = c0 + cb * 16 + (lane & 15);
            float b = bg[colg];
            #pragma unroll
            for (int reg = 0; reg < 4; ++reg) {
                float t = fmaxf(acc[rb][cb][reg] + b, 0.f);
                vv[rb][cb][reg] = t;
                ps[rb][reg] += t * t;
            }
        }
    #pragma unroll
    for (int msk = 1; msk < 16; msk <<= 1)
        #pragma unroll
        for (int rb = 0; rb < 2; ++rb)
            #pragma unroll
            for (int reg = 0; reg < 4; ++reg)
                ps[rb][reg] += __shfl_xor(ps[rb][reg], msk);
    if ((lane & 15) == 0) {
        #pragma unroll
        for (int rb = 0; rb < 2; ++rb)
            #pragma unroll
            for (int reg = 0; reg < 4; ++reg)
                ssq_l[r0 + rb * 16 + (lane >> 4) * 4 + reg][w >> 1] = ps[rb][reg];
    }
    __syncthreads();
    #pragma unroll
    for (int rb = 0; rb < 2; ++rb)
        #pragma unroll
        for (int reg = 0; reg < 4; ++reg) {
            int lr = r0 + rb * 16 + (lane >> 4) * 4 + reg;
            float s = ssq_l[lr][0] + ssq_l[lr][1];
            float sc = 1.0f / fmaxf(sqrtf(s), 1e-12f);
            int m = m0 + lr;
            #pragma unroll
            for (int cb = 0; cb < 4; ++cb) {
                int colg = c0 + cb * 16 + (lane & 15);
                float o = vv[rb][cb][reg] * sc;
                if (m < N_NODES) jk[(size_t)m * NH + colg] = o;
                if constexpr (WRITE_T) tb[colg * 64 + lr] = f2bf(o);
            }
        }
    if constexpr (WRITE_T) {
        __syncthreads();
        #pragma unroll
        for (int p = 0; p < 4; ++p) {
            int flat = (tid + p * 256) * 8;
            int c = flat >> 6, mo = flat & 63;
            int kglob = m0 + mo;
            if (kglob < KP) {
                unsigned short tmp[8];
                #pragma unroll
                for (int i = 0; i < 8; ++i)
                    tmp[i] = (kglob + i < N_NODES) ? tb[c * 64 + mo + i] : (unsigned short)0;
                ushort4 v0, v1;
                v0.x = tmp[0]; v0.y = tmp[1]; v0.z = tmp[2]; v0.w = tmp[3];
                v1.x = tmp[4]; v1.y = tmp[5]; v1.z = tmp[6]; v1.w = tmp[7];
                *(ushort4*)(jkT + (size_t)c * KP + kglob)     = v0;
                *(ushort4*)(jkT + (size_t)c * KP + kglob + 4) = v1;
            }
        }
    }
}

// ---------------------------------------------------------------------------
// Full LSTM JK chain in one kernel: 4 steps, h-states in LDS, c in registers.
// BM=32 rows/block, grid 313. Final step fuses JK-mean + bn_in + ELU -> hpost.
// ---------------------------------------------------------------------------
__global__ __launch_bounds__(256) void lstm4_kernel(
    const float* __restrict__ jk0, const float* __restrict__ jk1,
    const unsigned short* __restrict__ wl,   // [2][512][256] bf16
    const float* __restrict__ bih0, const float* __restrict__ bhh0,
    const float* __restrict__ bih1, const float* __restrict__ bhh1,
    const float* __restrict__ bng, const float* __restrict__ bnb,
    const float* __restrict__ bnrm, const float* __restrict__ bnrv,
    float* __restrict__ hpost)
{
    __shared__ unsigned short sa[32 * 32];
    __shared__ unsigned short sb[512 * 32];
    __shared__ unsigned short hb[2][32][136];   // +8 pad
    const int tid = threadIdx.x, lane = tid & 63, w = tid >> 6;
    const int m0 = blockIdx.x * 32;
    const int arow = tid >> 2, agrp = tid & 3;  // A staging (tid<128)
    const int mg = min(m0 + arow, N_NODES - 1);

    f32x4 acc[2][8];
    float cst[2][2][4];

    auto zacc = [&] {
        #pragma unroll
        for (int i = 0; i < 2; ++i)
            #pragma unroll
            for (int j = 0; j < 8; ++j) acc[i][j] = (f32x4){0.f, 0.f, 0.f, 0.f};
    };
    auto stage_sb = [&](const unsigned short* wlayer, int k0) {
        #pragma unroll
        for (int t = 0; t < 8; ++t) {
            int gi = tid + t * 256, n = gi >> 2, grp = gi & 3;
            *(bf16x8*)(sb + n * 32 + ((grp ^ (n & 3)) << 3)) =
                *(const bf16x8*)(wlayer + (size_t)n * 256 + k0 + grp * 8);
        }
    };
    auto stage_sa = [&](const float* a, int k0) {
        if (tid < 128) {
            int kg = k0 + agrp * 8;
            const float* src = a + (size_t)mg * NH + kg;
            float4 u0 = *(const float4*)src, u1 = *(const float4*)(src + 4);
            float a8[8] = {u0.x, u0.y, u0.z, u0.w, u1.x, u1.y, u1.z, u1.w};
            *(bf16x8*)(sa + arow * 32 + ((agrp ^ (arow & 3)) << 3)) = cvt8(a8);
        }
    };
    auto av_sa = [&](int rb) {
        int row = rb * 16 + (lane & 15), g = lane >> 4;
        return *(const bf16x8*)(sa + row * 32 + ((g ^ (row & 3)) << 3));
    };
    auto av_hb = [&](int i, int rb, int kl) {
        int row = rb * 16 + (lane & 15), g = lane >> 4;
        return *(const bf16x8*)(&hb[i][row][kl + g * 8]);
    };
    auto mfma_all = [&](bf16x8 a0, bf16x8 a1) {
        #pragma unroll
        for (int gate = 0; gate < 4; ++gate)
            #pragma unroll
            for (int cb = 0; cb < 2; ++cb) {
                int col = gate * 128 + w * 32 + cb * 16 + (lane & 15);
                int g = lane >> 4;
                bf16x8 bv = *(const bf16x8*)(sb + col * 32 + ((g ^ (col & 3)) << 3));
                acc[0][gate * 2 + cb] =
                    __builtin_amdgcn_mfma_f32_16x16x32_bf16(a0, bv, acc[0][gate * 2 + cb], 0, 0, 0);
                acc[1][gate * 2 + cb] =
                    __builtin_amdgcn_mfma_f32_16x16x32_bf16(a1, bv, acc[1][gate * 2 + cb], 0, 0, 0);
            }
    };
    auto epi = [&](const float* bih, const float* bhh, bool hasc, int hdst, bool fin) {
        __syncthreads();
        #pragma unroll
        for (int cb = 0; cb < 2; ++cb) {
            int cg = w * 32 + cb * 16 + (lane & 15);
            float bi  = bih[cg]       + bhh[cg];
            float bf_ = bih[128 + cg] + bhh[128 + cg];
            float bgg = bih[256 + cg] + bhh[256 + cg];
            float bo  = bih[384 + cg] + bhh[384 + cg];
            float sc = 0.f, sh = 0.f;
            if (fin) {
                sc = bng[cg] / sqrtf(bnrv[cg] + BN_EPS);
                sh = bnb[cg] - bnrm[cg] * sc;
            }
            #pragma unroll
            for (int rb = 0; rb < 2; ++rb)
                #pragma unroll
                for (int reg = 0; reg < 4; ++reg) {
                    int lr = rb * 16 + (lane >> 4) * 4 + reg;
                    float zi = acc[rb][0 + cb][reg] + bi;
                    float zf = acc[rb][2 + cb][reg] + bf_;
                    float zg = acc[rb][4 + cb][reg] + bgg;
                    float zo = acc[rb][6 + cb][reg] + bo;
                    float cn = sigm(zi) * tanhf(zg);
                    if (hasc) cn += sigm(zf) * cst[rb][cb][reg];
                    cst[rb][cb][reg] = cn;
                    float hv = sigm(zo) * tanhf(cn);
                    if (fin) {
                        float hm = bf2f(hb[0][lr][cg]);     // h2_0
                        float t = 0.5f * (hm + hv);
                        t = t * sc + sh;
                        int m = m0 + lr;
                        if (m < N_NODES) hpost[(size_t)m * NH + cg] = t > 0.f ? t : expm1f(t);
                    } else {
                        hb[hdst][lr][cg] = f2bf(hv);
                    }
                }
        }
        __syncthreads();
    };

    // step0: L1 t0, A = jk0, K=128
    zacc();
    for (int k0 = 0; k0 < 128; k0 += 32) {
        __syncthreads();
        stage_sa(jk0, k0);
        stage_sb(wl, k0);
        __syncthreads();
        mfma_all(av_sa(0), av_sa(1));
    }
    epi(bih0, bhh0, false, 0, false);           // h1_0 -> hb0

    // step1: L1 t1, A = [jk1 | hb0], K=256
    zacc();
    for (int k0 = 0; k0 < 256; k0 += 32) {
        __syncthreads();
        if (k0 < 128) stage_sa(jk1, k0);
        stage_sb(wl, k0);
        __syncthreads();
        if (k0 < 128) mfma_all(av_sa(0), av_sa(1));
        else          mfma_all(av_hb(0, 0, k0 - 128), av_hb(0, 1, k0 - 128));
    }
    epi(bih0, bhh0, true, 1, false);            // h1_1 -> hb1

    // step2: L2 t0, A = hb0 (h1_0), K=128
    const unsigned short* wl1 = wl + 512 * 256;
    zacc();
    for (int k0 = 0; k0 < 128; k0 += 32) {
        __syncthreads();
        stage_sb(wl1, k0);
        __syncthreads();
        mfma_all(av_hb(0, 0, k0), av_hb(0, 1, k0));
    }
    epi(bih1, bhh1, false, 0, false);           // h2_0 -> hb0

    // step3: L2 t1, A = [hb1 | hb0] = [h1_1 | h2_0], K=256, FINAL
    zacc();
    for (int k0 = 0; k0 < 256; k0 += 32) {
        __syncthreads();
        stage_sb(wl1, k0);
        __syncthreads();
        if (k0 < 128) mfma_all(av_hb(1, 0, k0), av_hb(1, 1, k0));
        else          mfma_all(av_hb(0, 0, k0 - 128), av_hb(0, 1, k0 - 128));
    }
    epi(bih1, bhh1, true, -1, true);            // hpost out
}

// ---------------------------------------------------------------------------
// Epilogue: e=elu(bn(embed@W_emb^T)) -> LDS; hfc=elu(bn([hpost|e]@W_fc^T))
// -> LDS; out = log_softmax(hfc@W_out^T + b). BM=64, grid MT.
// ---------------------------------------------------------------------------
__global__ __launch_bounds__(256) void epilogue_kernel(
    const float* __restrict__ embed,
    const float* __restrict__ W_emb, const float* __restrict__ b_emb,
    const float* __restrict__ bn_e_g, const float* __restrict__ bn_e_b,
    const float* __restrict__ bn_e_rm, const float* __restrict__ bn_e_rv,
    const float* __restrict__ hpost,
    const float* __restrict__ W_fc, const float* __restrict__ b_fc,
    const float* __restrict__ bn_f_g, const float* __restrict__ bn_f_b,
    const float* __restrict__ bn_f_rm, const float* __restrict__ bn_f_rv,
    const float* __restrict__ W_out, const float* __restrict__ b_out,
    float* __restrict__ out)
{
    __shared__ unsigned short sa[64 * 32];
    __shared__ unsigned short sb[192 * 32];
    __shared__ unsigned short ebuf[64][72];
    __shared__ float fbuf[64][204];
    const int tid = threadIdx.x, lane = tid & 63, w = tid >> 6;
    const int m0 = blockIdx.x * 64;
    const int arow = tid >> 2, agrp = tid & 3;
    const int mg = min(m0 + arow, N_NODES - 1);
    const int g = lane >> 4;

    // ---- phase E ----
    f32x4 aE[4];
    #pragma unroll
    for (int j = 0; j < 4; ++j) aE[j] = (f32x4){0.f, 0.f, 0.f, 0.f};
    for (int k0 = 0; k0 < NFE; k0 += 32) {
        float a8[8], b8[8];
        {
            const float* s = embed + (size_t)mg * NFE + k0 + agrp * 8;
            float4 u0 = *(const float4*)s, u1 = *(const float4*)(s + 4);
            a8[0]=u0.x; a8[1]=u0.y; a8[2]=u0.z; a8[3]=u0.w;
            a8[4]=u1.x; a8[5]=u1.y; a8[6]=u1.z; a8[7]=u1.w;
        }
        {
            const float* s = W_emb + (size_t)arow * NFE + k0 + agrp * 8;  // arow<64=NHE
            float4 u0 = *(const float4*)s, u1 = *(const float4*)(s + 4);
            b8[0]=u0.x; b8[1]=u0.y; b8[2]=u0.z; b8[3]=u0.w;
            b8[4]=u1.x; b8[5]=u1.y; b8[6]=u1.z; b8[7]=u1.w;
        }
        __syncthreads();
        *(bf16x8*)(sa + arow * 32 + ((agrp ^ (arow & 3)) << 3)) = cvt8(a8);
        *(bf16x8*)(sb + arow * 32 + ((agrp ^ (arow & 3)) << 3)) = cvt8(b8);
        __syncthreads();
        bf16x8 av;
        { int row = w * 16 + (lane & 15);
          av = *(const bf16x8*)(sa + row * 32 + ((g ^ (row & 3)) << 3)); }
        #pragma unroll
        for (int cb = 0; cb < 4; ++cb) {
            int col = cb * 16 + (lane & 15);
            bf16x8 bv = *(const bf16x8*)(sb + col * 32 + ((g ^ (col & 3)) << 3));
            aE[cb] = __builtin_amdgcn_mfma_f32_16x16x32_bf16(av, bv, aE[cb], 0, 0, 0);
        }
    }
    #pragma unroll
    for (int cb = 0; cb < 4; ++cb) {
        int col = cb * 16 + (lane & 15);
        float sc = bn_e_g[col] / sqrtf(bn_e_rv[col] + BN_EPS);
        float sh = bn_e_b[col] - bn_e_rm[col] * sc;
        float bb = b_emb[col];
        #pragma unroll
        for (int reg = 0; reg < 4; ++reg) {
            int row = w * 16 + (lane >> 4) * 4 + reg;
            float t = (aE[cb][reg] + bb) * sc + sh;
            ebuf[row][col] = f2bf(t > 0.f ? t : expm1f(t));
        }
    }
    __syncthreads();

    // ---- phase F ----
    f32x4 aF[4][3];
    #pragma unroll
    for (int i = 0; i < 4; ++i)
        #pragma unroll
        for (int j = 0; j < 3; ++j) aF[i][j] = (f32x4){0.f, 0.f, 0.f, 0.f};
    for (int k0 = 0; k0 < DCAT; k0 += 32) {
        const bool gl = (k0 < 128);
        float b8[3][8];
        #pragma unroll
        for (int t = 0; t < 3; ++t) {
            int gi = tid + t * 256, n = gi >> 2, grp = gi & 3;
            const float* s = W_fc + (size_t)n * DCAT + k0 + grp * 8;
            float4 u0 = *(const float4*)s, u1 = *(const float4*)(s + 4);
            b8[t][0]=u0.x; b8[t][1]=u0.y; b8[t][2]=u0.z; b8[t][3]=u0.w;
            b8[t][4]=u1.x; b8[t][5]=u1.y; b8[t][6]=u1.z; b8[t][7]=u1.w;
        }
        float a8[8];
        if (gl) {
            const float* s = hpost + (size_t)mg * NH + k0 + agrp * 8;
            float4 u0 = *(const float4*)s, u1 = *(const float4*)(s + 4);
            a8[0]=u0.x; a8[1]=u0.y; a8[2]=u0.z; a8[3]=u0.w;
            a8[4]=u1.x; a8[5]=u1.y; a8[6]=u1.z; a8[7]=u1.w;
        }
        __syncthreads();
        if (gl) *(bf16x8*)(sa + arow * 32 + ((agrp ^ (arow & 3)) << 3)) = cvt8(a8);
        #pragma unroll
        for (int t = 0; t < 3; ++t) {
            int gi = tid + t * 256, n = gi >> 2, grp = gi & 3;
            *(bf16x8*)(sb + n * 32 + ((grp ^ (n & 3)) << 3)) = cvt8(b8[t]);
        }
        __syncthreads();
        #pragma unroll
        for (int rf = 0; rf < 4; ++rf) {
            int row = rf * 16 + (lane & 15);
            bf16x8 av = gl ? *(const bf16x8*)(sa + row * 32 + ((g ^ (row & 3)) << 3))
                           : *(const bf16x8*)(&ebuf[row][(k0 - 128) + g * 8]);
            #pragma unroll
            for (int cf = 0; cf < 3; ++cf) {
                int col = w * 48 + cf * 16 + (lane & 15);
                bf16x8 bv = *(const bf16x8*)(sb + col * 32 + ((g ^ (col & 3)) << 3));
                aF[rf][cf] = __builtin_amdgcn_mfma_f32_16x16x32_bf16(av, bv, aF[rf][cf], 0, 0, 0);
            }
        }
    }
    #pragma unroll
    for (int cf = 0; cf < 3; ++cf) {
        int col = w * 48 + cf * 16 + (lane & 15);
        float sc = bn_f_g[col] / sqrtf(bn_f_rv[col] + BN_EPS);
        float sh = bn_f_b[col] - bn_f_rm[col] * sc;
        float bb = b_fc[col];
        #pragma unroll
        for (int rf = 0; rf < 4; ++rf)
            #pragma unroll
            for (int reg = 0; reg < 4; ++reg) {
                int row = rf * 16 + (lane >> 4) * 4 + reg;
                float t = (aF[rf][cf][reg] + bb) * sc + sh;
                fbuf[row][col] = t > 0.f ? t : expm1f(t);
            }
    }
    __syncthreads();

    // ---- phase O ----
    f32x4 aO[2];
    aO[0] = (f32x4){0.f, 0.f, 0.f, 0.f};
    aO[1] = (f32x4){0.f, 0.f, 0.f, 0.f};
    for (int k0 = 0; k0 < DCAT; k0 += 32) {
        float b8[8];
        const bool act = tid < 128;                       // 32 out-cols x 4 granules
        if (act) {
            if (arow < NOUT) {
                const float* s = W_out + (size_t)arow * DCAT + k0 + agrp * 8;
                float4 u0 = *(const float4*)s, u1 = *(const float4*)(s + 4);
                b8[0]=u0.x; b8[1]=u0.y; b8[2]=u0.z; b8[3]=u0.w;
                b8[4]=u1.x; b8[5]=u1.y; b8[6]=u1.z; b8[7]=u1.w;
            } else {
                #pragma unroll
                for (int i = 0; i < 8; ++i) b8[i] = 0.f;
            }
        }
        __syncthreads();
        if (act) *(bf16x8*)(sb + arow * 32 + ((agrp ^ (arow & 3)) << 3)) = cvt8(b8);
        __syncthreads();
        int row = w * 16 + (lane & 15);
        float4 f0 = *(const float4*)(&fbuf[row][k0 + g * 8]);
        float4 f1 = *(const float4*)(&fbuf[row][k0 + g * 8 + 4]);
        float f8[8] = {f0.x, f0.y, f0.z, f0.w, f1.x, f1.y, f1.z, f1.w};
        bf16x8 av = cvt8(f8);
        #pragma unroll
        for (int cf = 0; cf < 2; ++cf) {
            int col = cf * 16 + (lane & 15);
            bf16x8 bv = *(const bf16x8*)(sb + col * 32 + ((g ^ (col & 3)) << 3));
            aO[cf] = __builtin_amdgcn_mfma_f32_16x16x32_bf16(av, bv, aO[cf], 0, 0, 0);
        }
    }
    const int c0i = lane & 15, c1i = 16 + (lane & 15);
    const bool v1 = c1i < NOUT;
    #pragma unroll
    for (int reg = 0; reg < 4; ++reg) {
        int row = w * 16 + (lane >> 4) * 4 + reg;
        int m = m0 + row;
        float l0 = aO[0][reg] + b_out[c0i];
        float l1 = v1 ? (aO[1][reg] + b_out[c1i]) : -INFINITY;
        float mx = fmaxf(l0, l1);
        #pragma unroll
        for (int msk = 1; msk < 16; msk <<= 1) mx = fmaxf(mx, __shfl_xor(mx, msk));
        float s = expf(l0 - mx) + (v1 ? expf(l1 - mx) : 0.f);
        #pragma unroll
        for (int msk = 1; msk < 16; msk <<= 1) s += __shfl_xor(s, msk);
        float lse = mx + logf(s);
        if (m < N_NODES) {
            out[(size_t)m * NOUT + c0i] = l0 - lse;
            if (v1) out[(size_t)m * NOUT + c1i] = l1 - lse;
        }
    }
}

// ---------------------------------------------------------------------------
extern "C" void kernel_launch(void* const* d_in, const int* in_sizes, int n_in,
                              void* d_out, int out_size, void* d_ws, size_t ws_size,
                              hipStream_t stream)
{
    const float* x       = (const float*)d_in[0];
    const float* embed   = (const float*)d_in[1];
    const float* adj     = (const float*)d_in[2];
    const float* W_in    = (const float*)d_in[3];
    const float* b_in    = (const float*)d_in[4];
    const float* bn_in_g = (const float*)d_in[5];
    const float* bn_in_b = (const float*)d_in[6];
    const float* bn_in_rm= (const float*)d_in[7];
    const float* bn_in_rv= (const float*)d_in[8];
    const float* W_gs    = (const float*)d_in[9];
    const float* b_gs    = (const float*)d_in[10];
    const float* Wih0    = (const float*)d_in[11];
    const float* Whh0    = (const float*)d_in[12];
    const float* bih0    = (const float*)d_in[13];
    const float* bhh0    = (const float*)d_in[14];
    const float* Wih1    = (const float*)d_in[15];
    const float* Whh1    = (const float*)d_in[16];
    const float* bih1    = (const float*)d_in[17];
    const float* bhh1    = (const float*)d_in[18];
    const float* W_emb   = (const float*)d_in[19];
    const float* b_emb   = (const float*)d_in[20];
    const float* bn_e_g  = (const float*)d_in[21];
    const float* bn_e_b  = (const float*)d_in[22];
    const float* bn_e_rm = (const float*)d_in[23];
    const float* bn_e_rv = (const float*)d_in[24];
    const float* W_fc    = (const float*)d_in[25];
    const float* b_fc    = (const float*)d_in[26];
    const float* bn_f_g  = (const float*)d_in[27];
    const float* bn_f_b  = (const float*)d_in[28];
    const float* bn_f_rm = (const float*)d_in[29];
    const float* bn_f_rv = (const float*)d_in[30];
    const float* W_out   = (const float*)d_in[31];
    const float* b_out   = (const float*)d_in[32];
    float* outp = (float*)d_out;

    const size_t HB = (size_t)N_NODES * NH * sizeof(float);
    char* wp = (char*)d_ws;
    auto carve = [&](size_t bytes) {
        void* p = (void*)wp;
        wp += (bytes + 1023) & ~(size_t)1023;
        return p;
    };
    void* partRaw = carve((size_t)NSPLIT * MPAD * NH * 2);     // 41.2 MB (bf16 view)
    unsigned short* partB = (unsigned short*)partRaw;
    float* partF = (float*)partRaw;                             // xw f32 view (4 chunks fit)
    float* part_s= (float*)carve((size_t)NSPLIT * MPAD * sizeof(float));
    float* h_in  = (float*)carve(HB);
    float* jk0   = (float*)carve(HB);
    float* jk1   = (float*)carve(HB);
    float* hpost = (float*)carve(HB);
    unsigned short* hT  = (unsigned short*)carve((size_t)NH * KP * 2);
    unsigned short* wl  = (unsigned short*)carve((size_t)2 * 512 * 256 * 2);
    unsigned short* wgb = (unsigned short*)carve((size_t)2 * 128 * 256 * 2);
    if ((size_t)(wp - (char*)d_ws) > ws_size) return;

    const dim3 blk(256);

    // 1. h_in = elu(bn_in(x @ W_in.T + b_in)); also h_inT; weight packing folded in
    xw_mfma_kernel<<<dim3(MT, NSPLX), blk, 0, stream>>>(x, W_in, partF,
                                                        Wih0, Whh0, Wih1, Whh1, W_gs,
                                                        wl, wgb);
    xw_reduce_kernel<<<1250, blk, 0, stream>>>(partF, b_in, bn_in_g, bn_in_b,
                                               bn_in_rm, bn_in_rv, h_in, hT);

    // 2. GraphSAGE layer 0 (forward block order)
    adjmm_kernel<0><<<dim3(MT, NSPLIT), blk, 0, stream>>>(adj, hT, partB, part_s);
    gs_fused_kernel<true><<<MT, blk, 0, stream>>>(h_in, partB, part_s, wgb, b_gs, jk0, hT);

    // 3. GraphSAGE layer 1 (REVERSED block order -> L3 tail reuse of adj)
    adjmm_kernel<1><<<dim3(MT, NSPLIT), blk, 0, stream>>>(adj, hT, partB, part_s);
    gs_fused_kernel<false><<<MT, blk, 0, stream>>>(jk0, partB, part_s, wgb + 128 * 256,
                                                   b_gs + 128, jk1, nullptr);

    // 4. LSTM JK chain (4 steps in one kernel) + JK-mean + bn + elu
    lstm4_kernel<<<313, blk, 0, stream>>>(jk0, jk1, wl, bih0, bhh0, bih1, bhh1,
                                          bn_in_g, bn_in_b, bn_in_rm, bn_in_rv, hpost);

    // 5. emb + fc + log_softmax fused epilogue
    epilogue_kernel<<<MT, blk, 0, stream>>>(embed, W_emb, b_emb,
                                            bn_e_g, bn_e_b, bn_e_rm, bn_e_rv,
                                            hpost, W_fc, b_fc,
                                            bn_f_g, bn_f_b, bn_f_rm, bn_f_rv,
                                            W_out, b_out, outp);
}